// Round 6
// baseline (280.912 us; speedup 1.0000x reference)
//
#include <hip/hip_runtime.h>
#include <hip/hip_bf16.h>
#include <math.h>

#define NTOK 512      // N
#define BATCH 2
#define HID 256
#define HEADS 4
#define HD 64
#define NEG_INF -1e9f

typedef short bf16x8 __attribute__((ext_vector_type(8)));
typedef short bf16x4 __attribute__((ext_vector_type(4)));
typedef float f32x4 __attribute__((ext_vector_type(4)));
typedef float f32x2 __attribute__((ext_vector_type(2)));

__device__ __forceinline__ short f2bf(float f) {
    union { __hip_bfloat16 h; short s; } u;
    u.h = __float2bfloat16(f);
    return u.s;
}

// Branch-free gelu via A&S 7.1.26 erf (max erf err 1.5e-7). Scalar version.
__device__ __forceinline__ float fast_gelu(float x) {
    const float z = fabsf(x) * 0.70710678118654752f;
    const float t = __builtin_amdgcn_rcpf(fmaf(0.3275911f, z, 1.0f));
    float p = fmaf(0.530702714f, t, -0.726576013f);   // coeffs pre-scaled by 0.5
    p = fmaf(p, t, 0.710706871f);
    p = fmaf(p, t, -0.142248368f);
    p = fmaf(p, t, 0.127414796f);
    p = p * t;
    const float E = __builtin_amdgcn_exp2f(z * z * -1.44269504088896f);
    const float phin = p * E;                         // Phi(-|x|) in [0,0.5]
    const float phi = 0.5f + copysignf(0.5f - phin, x);
    return x * phi;
}

// Packed 2-wide gelu: float2 chains -> v_pk_fma_f32 for poly/fma portions.
__device__ __forceinline__ f32x2 fast_gelu2(f32x2 x) {
    f32x2 ax; ax[0] = fabsf(x[0]); ax[1] = fabsf(x[1]);
    const f32x2 z = ax * 0.70710678118654752f;
    const f32x2 q = z * 0.3275911f + 1.0f;
    f32x2 t; t[0] = __builtin_amdgcn_rcpf(q[0]); t[1] = __builtin_amdgcn_rcpf(q[1]);
    f32x2 p = t * 0.530702714f + (-0.726576013f);
    p = p * t + 0.710706871f;
    p = p * t + (-0.142248368f);
    p = p * t + 0.127414796f;
    p = p * t;
    const f32x2 e2 = (z * z) * (-1.44269504088896f);
    f32x2 E; E[0] = __builtin_amdgcn_exp2f(e2[0]); E[1] = __builtin_amdgcn_exp2f(e2[1]);
    const f32x2 phin = p * E;
    f32x2 phi;
    phi[0] = 0.5f + copysignf(0.5f - phin[0], x[0]);
    phi[1] = 0.5f + copysignf(0.5f - phin[1], x[1]);
    return x * phi;
}

// ---------------------------------------------------------------------------
// Stage A: fused 5-way projection GEMM.  Y = X @ W (+bias)
// ---------------------------------------------------------------------------
__global__ __launch_bounds__(256) void pga_proj5(
    const float* __restrict__ x,
    const float* __restrict__ Wq, const float* __restrict__ bq,
    const float* __restrict__ Wk, const float* __restrict__ bk,
    const float* __restrict__ Wv, const float* __restrict__ bv,
    const float* __restrict__ Wp1, const float* __restrict__ bp1,
    float* __restrict__ Q, float* __restrict__ K, float* __restrict__ V,
    float* __restrict__ A, float* __restrict__ BbT)
{
    __shared__ float xs[16][HID];
    const int m0 = blockIdx.x * 16;
    const int which = blockIdx.y;
    const int t = threadIdx.x;
    const int cg = t & 63;
    const int rg = t >> 6;

    {
        const float4* xg = (const float4*)(x + m0 * HID);
        float4* xsv = (float4*)xs;
        #pragma unroll
        for (int k = 0; k < 4; ++k) xsv[t + 256 * k] = xg[t + 256 * k];
    }
    __syncthreads();

    const float* W; const float* bvec; float* out; bool transposed = false;
    switch (which) {
        case 0: W = Wq; bvec = bq; out = Q; break;
        case 1: W = Wk; bvec = bk; out = K; break;
        case 2: W = Wv; bvec = bv; out = V; break;
        case 3: W = Wp1; bvec = bp1; out = A; break;
        default: W = Wp1 + HID * HID; bvec = nullptr; out = BbT; transposed = true; break;
    }

    float4 bias4 = make_float4(0.f, 0.f, 0.f, 0.f);
    if (bvec) bias4 = ((const float4*)bvec)[cg];
    float4 acc[4] = {bias4, bias4, bias4, bias4};

    const float4* W4 = (const float4*)W;
    for (int kq = 0; kq < 64; ++kq) {
        const float4 w0 = W4[(4 * kq + 0) * 64 + cg];
        const float4 w1 = W4[(4 * kq + 1) * 64 + cg];
        const float4 w2 = W4[(4 * kq + 2) * 64 + cg];
        const float4 w3 = W4[(4 * kq + 3) * 64 + cg];
        #pragma unroll
        for (int r = 0; r < 4; ++r) {
            const float4 xv = ((const float4*)xs[4 * rg + r])[kq];
            acc[r].x = fmaf(xv.x, w0.x, fmaf(xv.y, w1.x, fmaf(xv.z, w2.x, fmaf(xv.w, w3.x, acc[r].x))));
            acc[r].y = fmaf(xv.x, w0.y, fmaf(xv.y, w1.y, fmaf(xv.z, w2.y, fmaf(xv.w, w3.y, acc[r].y))));
            acc[r].z = fmaf(xv.x, w0.z, fmaf(xv.y, w1.z, fmaf(xv.z, w2.z, fmaf(xv.w, w3.z, acc[r].z))));
            acc[r].w = fmaf(xv.x, w0.w, fmaf(xv.y, w1.w, fmaf(xv.z, w2.w, fmaf(xv.w, w3.w, acc[r].w))));
        }
    }

    if (!transposed) {
        #pragma unroll
        for (int r = 0; r < 4; ++r)
            ((float4*)(out + (m0 + 4 * rg + r) * HID))[cg] = acc[r];
    } else {
        const int b = m0 >= NTOK;
        const int n0 = m0 - b * NTOK;
        #pragma unroll
        for (int r = 0; r < 4; ++r) {
            const int row = n0 + 4 * rg + r;
            float* ob = BbT + b * (HID * NTOK);
            ob[(4 * cg + 0) * NTOK + row] = acc[r].x;
            ob[(4 * cg + 1) * NTOK + row] = acc[r].y;
            ob[(4 * cg + 2) * NTOK + row] = acc[r].z;
            ob[(4 * cg + 3) * NTOK + row] = acc[r].w;
        }
    }
}

// ---------------------------------------------------------------------------
// Stage B: physics bias over valid pairs. 2 rows per block, 256 threads,
//   each thread owns 2 consecutive compacted slots -> float2 packed gelu
//   (v_pk_fma_f32). grid = B*N/2 = 512 blocks (2 blocks/CU).
// ---------------------------------------------------------------------------
__global__ __launch_bounds__(256) void pga_bias(
    const float* __restrict__ A, const float* __restrict__ BbT,
    const float* __restrict__ Wp2, const float* __restrict__ bp2,
    const int* __restrict__ adj, float* __restrict__ biasg)
{
    __shared__ float as[2][HID];
    __shared__ float4 wp[HID];
    __shared__ short jlist[2][NTOK];
    __shared__ int wcnt[2][8];    // [row][half*4 + wave]

    const int t = threadIdx.x;    // 0..255
    const int b = blockIdx.x >> 8;
    const int i0 = (blockIdx.x & 255) * 2;
    const int w = t >> 6, lane = t & 63;
    const unsigned long long ltm = (1ull << lane) - 1ull;

    as[0][t] = A[(b * NTOK + i0 + 0) * HID + t];
    as[1][t] = A[(b * NTOK + i0 + 1) * HID + t];
    wp[t] = ((const float4*)Wp2)[t];

    // ---- ordered ballot compaction of both rows (j = half*256 + w*64 + lane) ----
    bool mm[2][2]; unsigned long long bms[2][2];
    #pragma unroll
    for (int r = 0; r < 2; ++r)
        #pragma unroll
        for (int hh = 0; hh < 2; ++hh) {
            const int j = hh * 256 + t;
            mm[r][hh] = adj[(i0 + r) * NTOK + j] > 0;
            bms[r][hh] = __ballot(mm[r][hh]);
            if (lane == 0) wcnt[r][hh * 4 + w] = __popcll(bms[r][hh]);
        }
    __syncthreads();

    int tot[2], base[2][2];
    #pragma unroll
    for (int r = 0; r < 2; ++r) {
        int run = 0;
        #pragma unroll
        for (int idx = 0; idx < 8; ++idx) {
            if (idx == w)     base[r][0] = run;
            if (idx == 4 + w) base[r][1] = run;
            run += wcnt[r][idx];
        }
        tot[r] = run;
    }
    #pragma unroll
    for (int r = 0; r < 2; ++r)
        #pragma unroll
        for (int hh = 0; hh < 2; ++hh)
            if (mm[r][hh])
                jlist[r][base[r][hh] + __popcll(bms[r][hh] & ltm)] = (short)(hh * 256 + t);
    __syncthreads();

    const int ct = tot[0] + tot[1];
    const float* bb = BbT + b * (HID * NTOK);
    const float4 bp = *(const float4*)bp2;

    for (int k0 = 2 * t; k0 < ct; k0 += 512) {
        const int k1 = k0 + 1;
        if (k1 < ct) {
            const int r0 = k0 >= tot[0], r1 = k1 >= tot[0];
            const int j0 = jlist[r0][k0 - (r0 ? tot[0] : 0)];
            const int j1 = jlist[r1][k1 - (r1 ? tot[0] : 0)];
            const float* a0 = as[r0];
            const float* a1 = as[r1];
            f32x2 ah0 = {0.f, 0.f}, ah1 = {0.f, 0.f}, ah2 = {0.f, 0.f}, ah3 = {0.f, 0.f};
            #pragma unroll 2
            for (int d = 0; d < HID; ++d) {
                f32x2 xv;
                xv[0] = a0[d] + bb[d * NTOK + j0];
                xv[1] = a1[d] + bb[d * NTOK + j1];
                const f32x2 g = fast_gelu2(xv);
                const float4 wv = wp[d];
                ah0 += g * wv.x; ah1 += g * wv.y;
                ah2 += g * wv.z; ah3 += g * wv.w;
            }
            float* o0 = biasg + (((size_t)b * HEADS) * NTOK + (i0 + r0)) * NTOK + j0;
            float* o1 = biasg + (((size_t)b * HEADS) * NTOK + (i0 + r1)) * NTOK + j1;
            o0[0 * NTOK * NTOK] = ah0[0] + bp.x; o0[1 * NTOK * NTOK] = ah1[0] + bp.y;
            o0[2 * NTOK * NTOK] = ah2[0] + bp.z; o0[3 * NTOK * NTOK] = ah3[0] + bp.w;
            o1[0 * NTOK * NTOK] = ah0[1] + bp.x; o1[1 * NTOK * NTOK] = ah1[1] + bp.y;
            o1[2 * NTOK * NTOK] = ah2[1] + bp.z; o1[3 * NTOK * NTOK] = ah3[1] + bp.w;
        } else {
            const int r0 = k0 >= tot[0];
            const int j0 = jlist[r0][k0 - (r0 ? tot[0] : 0)];
            const float* a0 = as[r0];
            float s0 = 0.f, s1 = 0.f, s2 = 0.f, s3 = 0.f;
            #pragma unroll 4
            for (int d = 0; d < HID; ++d) {
                const float g = fast_gelu(a0[d] + bb[d * NTOK + j0]);
                const float4 wv = wp[d];
                s0 = fmaf(g, wv.x, s0); s1 = fmaf(g, wv.y, s1);
                s2 = fmaf(g, wv.z, s2); s3 = fmaf(g, wv.w, s3);
            }
            float* o0 = biasg + (((size_t)b * HEADS) * NTOK + (i0 + r0)) * NTOK + j0;
            o0[0 * NTOK * NTOK] = s0 + bp.x; o0[1 * NTOK * NTOK] = s1 + bp.y;
            o0[2 * NTOK * NTOK] = s2 + bp.z; o0[3 * NTOK * NTOK] = s3 + bp.w;
        }
    }
}

// ---------------------------------------------------------------------------
// Stage C: MFMA attention, flash-decoding j-split. grid = 256 blocks =
//   (b, h, qt, js): each block does ONE 128-j tile for 64 q-rows, writing
//   unnormalized O-partial + per-row (m, l). Merge happens in pga_outproj.
// ---------------------------------------------------------------------------
#define KT_STRIDE 72
#define VN_STRIDE 76
#define PL_STRIDE 136

__global__ __launch_bounds__(256) void pga_attn(
    const float* __restrict__ Q, const float* __restrict__ K,
    const float* __restrict__ V, const float* __restrict__ biasg,
    const int* __restrict__ adj,
    float* __restrict__ op0, float* __restrict__ op1,
    float* __restrict__ op2, float* __restrict__ op3,
    float* __restrict__ mlbuf)
{
    __shared__ short Kt[128 * KT_STRIDE];
    __shared__ short Vn[128 * VN_STRIDE];
    __shared__ short Pl[4][16 * PL_STRIDE];

    const int blk = blockIdx.x;
    const int js = blk & 3;
    const int qt = (blk >> 2) & 7;
    const int h  = (blk >> 5) & 3;
    const int b  = blk >> 7;
    const int t = threadIdx.x;
    const int w = t >> 6;
    const int lane = t & 63;
    const int ln15 = lane & 15;
    const int quad = lane >> 4;

    float* Opart = (js == 0) ? op0 : (js == 1) ? op1 : (js == 2) ? op2 : op3;
    const int j0 = js * 128;
    const int i0w = qt * 64 + w * 16;

    // ---- Q A-fragments (scale folded into bf16 conversion) ----
    bf16x8 aq0, aq1;
    {
        const float* qrow = Q + ((size_t)(b * NTOK) + i0w + ln15) * HID + h * HD;
        const int k0 = quad * 8;
        #pragma unroll
        for (int jj = 0; jj < 8; ++jj) {
            aq0[jj] = f2bf(qrow[k0 + jj] * 0.125f);
            aq1[jj] = f2bf(qrow[32 + k0 + jj] * 0.125f);
        }
    }

    // ---- stage K,V tile ----
    for (int k = 0; k < 8; ++k) {
        const int flat4 = k * 256 + t;
        const int jl = flat4 >> 4, dq = flat4 & 15;
        const float4 kv = ((const float4*)(K + ((size_t)(b * NTOK) + j0 + jl) * HID + h * HD))[dq];
        const float4 vv = ((const float4*)(V + ((size_t)(b * NTOK) + j0 + jl) * HID + h * HD))[dq];
        bf16x4 ks, vs;
        ks[0] = f2bf(kv.x); ks[1] = f2bf(kv.y); ks[2] = f2bf(kv.z); ks[3] = f2bf(kv.w);
        vs[0] = f2bf(vv.x); vs[1] = f2bf(vv.y); vs[2] = f2bf(vv.z); vs[3] = f2bf(vv.w);
        *(bf16x4*)&Kt[jl * KT_STRIDE + dq * 4] = ks;
        *(bf16x4*)&Vn[jl * VN_STRIDE + dq * 4] = vs;
    }
    __syncthreads();

    // ---- S = Q K^T ----
    f32x4 s[8];
    #pragma unroll
    for (int nt = 0; nt < 8; ++nt) {
        const int krow = nt * 16 + ln15;
        const bf16x8 bk0 = *(const bf16x8*)&Kt[krow * KT_STRIDE + quad * 8];
        const bf16x8 bk1 = *(const bf16x8*)&Kt[krow * KT_STRIDE + 32 + quad * 8];
        f32x4 acc = (f32x4){0.f, 0.f, 0.f, 0.f};
        acc = __builtin_amdgcn_mfma_f32_16x16x32_bf16(aq0, bk0, acc, 0, 0, 0);
        acc = __builtin_amdgcn_mfma_f32_16x16x32_bf16(aq1, bk1, acc, 0, 0, 0);
        s[nt] = acc;
    }

    // ---- add masked bias ----
    const float* bgb = biasg + ((size_t)(b * HEADS + h)) * NTOK * NTOK;
    #pragma unroll
    for (int nt = 0; nt < 8; ++nt) {
        const int j = j0 + nt * 16 + ln15;
        #pragma unroll
        for (int r = 0; r < 4; ++r) {
            const int i = i0w + quad * 4 + r;
            const float bvv = bgb[(size_t)i * NTOK + j];
            const int mv = adj[i * NTOK + j];
            s[nt][r] += (mv > 0) ? bvv : NEG_INF;
        }
    }

    // ---- single-tile softmax stats ----
    float p[8][4], m_r[4], l_r[4];
    #pragma unroll
    for (int r = 0; r < 4; ++r) {
        float mx = s[0][r];
        #pragma unroll
        for (int nt = 1; nt < 8; ++nt) mx = fmaxf(mx, s[nt][r]);
        #pragma unroll
        for (int off = 1; off < 16; off <<= 1) mx = fmaxf(mx, __shfl_xor(mx, off, 64));
        float rs = 0.f;
        #pragma unroll
        for (int nt = 0; nt < 8; ++nt) { p[nt][r] = __expf(s[nt][r] - mx); rs += p[nt][r]; }
        #pragma unroll
        for (int off = 1; off < 16; off <<= 1) rs += __shfl_xor(rs, off, 64);
        m_r[r] = mx; l_r[r] = rs;
    }

    // ---- P -> per-wave LDS (C-layout scatter), read back as A-frags ----
    #pragma unroll
    for (int nt = 0; nt < 8; ++nt)
        #pragma unroll
        for (int r = 0; r < 4; ++r)
            Pl[w][(quad * 4 + r) * PL_STRIDE + nt * 16 + ln15] = f2bf(p[nt][r]);

    bf16x8 ap[4];
    #pragma unroll
    for (int kt = 0; kt < 4; ++kt)
        ap[kt] = *(const bf16x8*)&Pl[w][ln15 * PL_STRIDE + kt * 32 + quad * 8];

    // ---- O_partial = P V (unnormalized) ----
    f32x4 o_acc[4];
    #pragma unroll
    for (int dt = 0; dt < 4; ++dt) o_acc[dt] = (f32x4){0.f, 0.f, 0.f, 0.f};
    #pragma unroll
    for (int dt = 0; dt < 4; ++dt) {
        #pragma unroll
        for (int kt = 0; kt < 4; ++kt) {
            bf16x8 bv;
            #pragma unroll
            for (int jj = 0; jj < 8; ++jj)
                bv[jj] = Vn[(kt * 32 + quad * 8 + jj) * VN_STRIDE + dt * 16 + ln15];
            o_acc[dt] = __builtin_amdgcn_mfma_f32_16x16x32_bf16(ap[kt], bv, o_acc[dt], 0, 0, 0);
        }
    }

    // ---- write partials ----
    #pragma unroll
    for (int dt = 0; dt < 4; ++dt)
        #pragma unroll
        for (int r = 0; r < 4; ++r) {
            const int i = i0w + quad * 4 + r;
            Opart[((size_t)(b * NTOK) + i) * HID + h * HD + dt * 16 + ln15] = o_acc[dt][r];
        }
    if (ln15 == 0) {
        #pragma unroll
        for (int r = 0; r < 4; ++r) {
            const int i = i0w + quad * 4 + r;
            float* mlp = mlbuf + (((size_t)(js * BATCH + b) * NTOK + i) * HEADS + h) * 2;
            mlp[0] = m_r[r]; mlp[1] = l_r[r];
        }
    }
}

// ---------------------------------------------------------------------------
// Stage D: merge attention partials (flash-decode combine) + out = O@Wo + bo
// ---------------------------------------------------------------------------
__global__ __launch_bounds__(256) void pga_outproj(
    const float* __restrict__ op0, const float* __restrict__ op1,
    const float* __restrict__ op2, const float* __restrict__ op3,
    const float* __restrict__ mlbuf,
    const float* __restrict__ Wo, const float* __restrict__ bo,
    float* __restrict__ out)
{
    __shared__ float xs[16][HID];
    const int m0 = blockIdx.x * 16;
    const int t = threadIdx.x;
    const int c = t;
    const int h = c >> 6;

    const float* ops[4] = {op0, op1, op2, op3};

    #pragma unroll 4
    for (int r = 0; r < 16; ++r) {
        const int ig = m0 + r;
        const int b = ig >> 9, i = ig & 511;
        float po[4], ms[4], ls[4];
        #pragma unroll
        for (int s = 0; s < 4; ++s) {
            po[s] = ops[s][(size_t)ig * HID + c];
            const float* mlp = mlbuf + (((size_t)(s * BATCH + b) * NTOK + i) * HEADS + h) * 2;
            ms[s] = mlp[0]; ls[s] = mlp[1];
        }
        const float mmax = fmaxf(fmaxf(ms[0], ms[1]), fmaxf(ms[2], ms[3]));
        float L = 0.f, val = 0.f;
        #pragma unroll
        for (int s = 0; s < 4; ++s) {
            const float e = __expf(ms[s] - mmax);
            L += ls[s] * e;
            val = fmaf(po[s], e, val);
        }
        xs[r][c] = val / L;
    }
    __syncthreads();

    const int cg = t & 63;
    const int rg = t >> 6;
    const float4 bias4 = ((const float4*)bo)[cg];
    float4 acc[4] = {bias4, bias4, bias4, bias4};

    const float4* W4 = (const float4*)Wo;
    for (int kq = 0; kq < 64; ++kq) {
        const float4 w0 = W4[(4 * kq + 0) * 64 + cg];
        const float4 w1 = W4[(4 * kq + 1) * 64 + cg];
        const float4 w2 = W4[(4 * kq + 2) * 64 + cg];
        const float4 w3 = W4[(4 * kq + 3) * 64 + cg];
        #pragma unroll
        for (int r = 0; r < 4; ++r) {
            const float4 xv = ((const float4*)xs[4 * rg + r])[kq];
            acc[r].x = fmaf(xv.x, w0.x, fmaf(xv.y, w1.x, fmaf(xv.z, w2.x, fmaf(xv.w, w3.x, acc[r].x))));
            acc[r].y = fmaf(xv.x, w0.y, fmaf(xv.y, w1.y, fmaf(xv.z, w2.y, fmaf(xv.w, w3.y, acc[r].y))));
            acc[r].z = fmaf(xv.x, w0.z, fmaf(xv.y, w1.z, fmaf(xv.z, w2.z, fmaf(xv.w, w3.z, acc[r].z))));
            acc[r].w = fmaf(xv.x, w0.w, fmaf(xv.y, w1.w, fmaf(xv.z, w2.w, fmaf(xv.w, w3.w, acc[r].w))));
        }
    }
    #pragma unroll
    for (int r = 0; r < 4; ++r)
        ((float4*)(out + (m0 + 4 * rg + r) * HID))[cg] = acc[r];
}

extern "C" void kernel_launch(void* const* d_in, const int* in_sizes, int n_in,
                              void* d_out, int out_size, void* d_ws, size_t ws_size,
                              hipStream_t stream) {
    const float* x   = (const float*)d_in[0];
    const int*   adj = (const int*)d_in[1];
    const float* Wq  = (const float*)d_in[2];
    const float* bq  = (const float*)d_in[3];
    const float* Wk  = (const float*)d_in[4];
    const float* bk  = (const float*)d_in[5];
    const float* Wv  = (const float*)d_in[6];
    const float* bv  = (const float*)d_in[7];
    const float* Wo  = (const float*)d_in[8];
    const float* bo  = (const float*)d_in[9];
    const float* Wp1 = (const float*)d_in[10];
    const float* bp1 = (const float*)d_in[11];
    const float* Wp2 = (const float*)d_in[12];
    const float* bp2 = (const float*)d_in[13];
    float* out = (float*)d_out;

    // ws layout (floats), ~15.9 MB total. A/BbT die after pga_bias and are
    // reused as Opart[0]/Opart[1] by pga_attn (same-stream ordering).
    float* ws   = (float*)d_ws;
    float* Q    = ws;
    float* K    = ws + 262144;
    float* V    = ws + 2 * 262144;
    float* A    = ws + 3 * 262144;     // -> Opart[0]
    float* BbT  = ws + 4 * 262144;     // -> Opart[1]
    float* bias = ws + 5 * 262144;     // 2097152 floats
    float* Op2  = ws + 5 * 262144 + 2097152;
    float* Op3  = Op2 + 262144;
    float* mlb  = Op3 + 262144;        // 32768 floats

    pga_proj5<<<dim3(64, 5), 256, 0, stream>>>(x, Wq, bq, Wk, bk, Wv, bv,
                                               Wp1, bp1, Q, K, V, A, BbT);
    pga_bias<<<512, 256, 0, stream>>>(A, BbT, Wp2, bp2, adj, bias);
    pga_attn<<<256, 256, 0, stream>>>(Q, K, V, bias, adj, A, BbT, Op2, Op3, mlb);
    pga_outproj<<<64, 256, 0, stream>>>(A, BbT, Op2, Op3, mlb, Wo, bo, out);
}

// Round 7
// 210.423 us; speedup vs baseline: 1.3350x; 1.3350x over previous
//
#include <hip/hip_runtime.h>
#include <hip/hip_bf16.h>
#include <math.h>

#define NTOK 512      // N
#define BATCH 2
#define HID 256
#define HEADS 4
#define HD 64
#define NEG_INF -1e9f

typedef short bf16x8 __attribute__((ext_vector_type(8)));
typedef short bf16x4 __attribute__((ext_vector_type(4)));
typedef float f32x4 __attribute__((ext_vector_type(4)));

__device__ __forceinline__ short f2bf(float f) {
    union { __hip_bfloat16 h; short s; } u;
    u.h = __float2bfloat16(f);
    return u.s;
}

// Branch-free gelu via A&S 7.1.26 erf (max erf err 1.5e-7), exp2-based,
// poly coeffs pre-scaled by 0.5.
__device__ __forceinline__ float fast_gelu(float x) {
    const float z = fabsf(x) * 0.70710678118654752f;
    const float t = __builtin_amdgcn_rcpf(fmaf(0.3275911f, z, 1.0f));
    float p = fmaf(0.530702714f, t, -0.726576013f);
    p = fmaf(p, t, 0.710706871f);
    p = fmaf(p, t, -0.142248368f);
    p = fmaf(p, t, 0.127414796f);
    p = p * t;
    const float E = __builtin_amdgcn_exp2f(z * z * -1.44269504088896f);
    const float phin = p * E;                         // Phi(-|x|) in [0,0.5]
    const float phi = 0.5f + copysignf(0.5f - phin, x);
    return x * phi;
}

// ---------------------------------------------------------------------------
// Stage A: fused 5-way projection GEMM.  Y = X @ W (+bias)
// ---------------------------------------------------------------------------
__global__ __launch_bounds__(256) void pga_proj5(
    const float* __restrict__ x,
    const float* __restrict__ Wq, const float* __restrict__ bq,
    const float* __restrict__ Wk, const float* __restrict__ bk,
    const float* __restrict__ Wv, const float* __restrict__ bv,
    const float* __restrict__ Wp1, const float* __restrict__ bp1,
    float* __restrict__ Q, float* __restrict__ K, float* __restrict__ V,
    float* __restrict__ A, float* __restrict__ BbT)
{
    __shared__ float xs[16][HID];
    const int m0 = blockIdx.x * 16;
    const int which = blockIdx.y;
    const int t = threadIdx.x;
    const int cg = t & 63;
    const int rg = t >> 6;

    {
        const float4* xg = (const float4*)(x + m0 * HID);
        float4* xsv = (float4*)xs;
        #pragma unroll
        for (int k = 0; k < 4; ++k) xsv[t + 256 * k] = xg[t + 256 * k];
    }
    __syncthreads();

    const float* W; const float* bvec; float* out; bool transposed = false;
    switch (which) {
        case 0: W = Wq; bvec = bq; out = Q; break;
        case 1: W = Wk; bvec = bk; out = K; break;
        case 2: W = Wv; bvec = bv; out = V; break;
        case 3: W = Wp1; bvec = bp1; out = A; break;
        default: W = Wp1 + HID * HID; bvec = nullptr; out = BbT; transposed = true; break;
    }

    float4 bias4 = make_float4(0.f, 0.f, 0.f, 0.f);
    if (bvec) bias4 = ((const float4*)bvec)[cg];
    float4 acc[4] = {bias4, bias4, bias4, bias4};

    const float4* W4 = (const float4*)W;
    for (int kq = 0; kq < 64; ++kq) {
        const float4 w0 = W4[(4 * kq + 0) * 64 + cg];
        const float4 w1 = W4[(4 * kq + 1) * 64 + cg];
        const float4 w2 = W4[(4 * kq + 2) * 64 + cg];
        const float4 w3 = W4[(4 * kq + 3) * 64 + cg];
        #pragma unroll
        for (int r = 0; r < 4; ++r) {
            const float4 xv = ((const float4*)xs[4 * rg + r])[kq];
            acc[r].x = fmaf(xv.x, w0.x, fmaf(xv.y, w1.x, fmaf(xv.z, w2.x, fmaf(xv.w, w3.x, acc[r].x))));
            acc[r].y = fmaf(xv.x, w0.y, fmaf(xv.y, w1.y, fmaf(xv.z, w2.y, fmaf(xv.w, w3.y, acc[r].y))));
            acc[r].z = fmaf(xv.x, w0.z, fmaf(xv.y, w1.z, fmaf(xv.z, w2.z, fmaf(xv.w, w3.z, acc[r].z))));
            acc[r].w = fmaf(xv.x, w0.w, fmaf(xv.y, w1.w, fmaf(xv.z, w2.w, fmaf(xv.w, w3.w, acc[r].w))));
        }
    }

    if (!transposed) {
        #pragma unroll
        for (int r = 0; r < 4; ++r)
            ((float4*)(out + (m0 + 4 * rg + r) * HID))[cg] = acc[r];
    } else {
        const int b = m0 >= NTOK;
        const int n0 = m0 - b * NTOK;
        #pragma unroll
        for (int r = 0; r < 4; ++r) {
            const int row = n0 + 4 * rg + r;
            float* ob = BbT + b * (HID * NTOK);
            ob[(4 * cg + 0) * NTOK + row] = acc[r].x;
            ob[(4 * cg + 1) * NTOK + row] = acc[r].y;
            ob[(4 * cg + 2) * NTOK + row] = acc[r].z;
            ob[(4 * cg + 3) * NTOK + row] = acc[r].w;
        }
    }
}

// ---------------------------------------------------------------------------
// Stage B: physics bias over valid pairs. Two rows per block, self-compacted
//   into LDS. 576 threads (9 waves): combined count ct ~ 512+-16, so the
//   whole block finishes in ONE pass essentially always (fallback loop for
//   the 4-sigma tail keeps correctness). 1 pair per lane = max coalescing.
// ---------------------------------------------------------------------------
__global__ __launch_bounds__(576) void pga_bias(
    const float* __restrict__ A, const float* __restrict__ BbT,
    const float* __restrict__ Wp2, const float* __restrict__ bp2,
    const int* __restrict__ adj, float* __restrict__ biasg)
{
    __shared__ float as[2][HID];
    __shared__ float4 wp[HID];
    __shared__ short jlist[2][NTOK];
    __shared__ int wcnt[2][9];

    const int t = threadIdx.x;          // 0..575
    const int b = blockIdx.x >> 8;
    const int i0 = (blockIdx.x & 255) * 2;
    const int w = t >> 6, lane = t & 63;
    const unsigned long long ltm = (1ull << lane) - 1ull;

    if (t < 2 * HID) as[t >> 8][t & 255] = A[(b * NTOK + i0 + (t >> 8)) * HID + (t & 255)];
    if (t < HID) wp[t] = ((const float4*)Wp2)[t];

    // ---- ordered ballot compaction of rows i0, i0+1 (j = t for t<512) ----
    bool m0 = false, m1 = false;
    if (t < NTOK) {
        m0 = adj[(i0 + 0) * NTOK + t] > 0;
        m1 = adj[(i0 + 1) * NTOK + t] > 0;
    }
    const unsigned long long bm0 = __ballot(m0);
    const unsigned long long bm1 = __ballot(m1);
    if (lane == 0) { wcnt[0][w] = __popcll(bm0); wcnt[1][w] = __popcll(bm1); }
    __syncthreads();
    int base0 = 0, base1 = 0, tot0 = 0, tot1 = 0;
    #pragma unroll
    for (int w2 = 0; w2 < 9; ++w2) {
        const int c0 = wcnt[0][w2], c1 = wcnt[1][w2];
        if (w2 < w) { base0 += c0; base1 += c1; }
        tot0 += c0; tot1 += c1;
    }
    if (m0) jlist[0][base0 + __popcll(bm0 & ltm)] = (short)t;
    if (m1) jlist[1][base1 + __popcll(bm1 & ltm)] = (short)t;
    __syncthreads();

    // ---- main: one valid pair per lane (single pass in practice) ----
    const int ct = tot0 + tot1;
    const float* bb = BbT + b * (HID * NTOK);
    const float4 bp = *(const float4*)bp2;

    for (int idx = t; idx < ct; idx += 576) {
        const int r = idx >= tot0;
        const int j = jlist[r][idx - (r ? tot0 : 0)];
        const float* asr = as[r];
        float ah0 = 0.f, ah1 = 0.f, ah2 = 0.f, ah3 = 0.f;
        #pragma unroll 4
        for (int d = 0; d < HID; ++d) {
            const float g = fast_gelu(asr[d] + bb[d * NTOK + j]);
            const float4 wv = wp[d];
            ah0 = fmaf(g, wv.x, ah0); ah1 = fmaf(g, wv.y, ah1);
            ah2 = fmaf(g, wv.z, ah2); ah3 = fmaf(g, wv.w, ah3);
        }
        const int i = i0 + r;
        float* o = biasg + (((size_t)b * HEADS) * NTOK + i) * NTOK + j;
        o[0 * NTOK * NTOK] = ah0 + bp.x;
        o[1 * NTOK * NTOK] = ah1 + bp.y;
        o[2 * NTOK * NTOK] = ah2 + bp.z;
        o[3 * NTOK * NTOK] = ah3 + bp.w;
    }
}

// ---------------------------------------------------------------------------
// Stage C: MFMA attention, flash-decoding j-split. grid = 256 blocks =
//   (b, h, qt, js): each block does ONE 128-j tile for 64 q-rows, writing
//   unnormalized O-partial + per-row (m, l). Merge happens in pga_outproj.
// ---------------------------------------------------------------------------
#define KT_STRIDE 72
#define VN_STRIDE 76
#define PL_STRIDE 136

__global__ __launch_bounds__(256) void pga_attn(
    const float* __restrict__ Q, const float* __restrict__ K,
    const float* __restrict__ V, const float* __restrict__ biasg,
    const int* __restrict__ adj,
    float* __restrict__ op0, float* __restrict__ op1,
    float* __restrict__ op2, float* __restrict__ op3,
    float* __restrict__ mlbuf)
{
    __shared__ short Kt[128 * KT_STRIDE];
    __shared__ short Vn[128 * VN_STRIDE];
    __shared__ short Pl[4][16 * PL_STRIDE];

    const int blk = blockIdx.x;
    const int js = blk & 3;
    const int qt = (blk >> 2) & 7;
    const int h  = (blk >> 5) & 3;
    const int b  = blk >> 7;
    const int t = threadIdx.x;
    const int w = t >> 6;
    const int lane = t & 63;
    const int ln15 = lane & 15;
    const int quad = lane >> 4;

    float* Opart = (js == 0) ? op0 : (js == 1) ? op1 : (js == 2) ? op2 : op3;
    const int j0 = js * 128;
    const int i0w = qt * 64 + w * 16;

    // ---- Q A-fragments (scale folded into bf16 conversion) ----
    bf16x8 aq0, aq1;
    {
        const float* qrow = Q + ((size_t)(b * NTOK) + i0w + ln15) * HID + h * HD;
        const int k0 = quad * 8;
        #pragma unroll
        for (int jj = 0; jj < 8; ++jj) {
            aq0[jj] = f2bf(qrow[k0 + jj] * 0.125f);
            aq1[jj] = f2bf(qrow[32 + k0 + jj] * 0.125f);
        }
    }

    // ---- stage K,V tile ----
    for (int k = 0; k < 8; ++k) {
        const int flat4 = k * 256 + t;
        const int jl = flat4 >> 4, dq = flat4 & 15;
        const float4 kv = ((const float4*)(K + ((size_t)(b * NTOK) + j0 + jl) * HID + h * HD))[dq];
        const float4 vv = ((const float4*)(V + ((size_t)(b * NTOK) + j0 + jl) * HID + h * HD))[dq];
        bf16x4 ks, vs;
        ks[0] = f2bf(kv.x); ks[1] = f2bf(kv.y); ks[2] = f2bf(kv.z); ks[3] = f2bf(kv.w);
        vs[0] = f2bf(vv.x); vs[1] = f2bf(vv.y); vs[2] = f2bf(vv.z); vs[3] = f2bf(vv.w);
        *(bf16x4*)&Kt[jl * KT_STRIDE + dq * 4] = ks;
        *(bf16x4*)&Vn[jl * VN_STRIDE + dq * 4] = vs;
    }
    __syncthreads();

    // ---- S = Q K^T ----
    f32x4 s[8];
    #pragma unroll
    for (int nt = 0; nt < 8; ++nt) {
        const int krow = nt * 16 + ln15;
        const bf16x8 bk0 = *(const bf16x8*)&Kt[krow * KT_STRIDE + quad * 8];
        const bf16x8 bk1 = *(const bf16x8*)&Kt[krow * KT_STRIDE + 32 + quad * 8];
        f32x4 acc = (f32x4){0.f, 0.f, 0.f, 0.f};
        acc = __builtin_amdgcn_mfma_f32_16x16x32_bf16(aq0, bk0, acc, 0, 0, 0);
        acc = __builtin_amdgcn_mfma_f32_16x16x32_bf16(aq1, bk1, acc, 0, 0, 0);
        s[nt] = acc;
    }

    // ---- add masked bias ----
    const float* bgb = biasg + ((size_t)(b * HEADS + h)) * NTOK * NTOK;
    #pragma unroll
    for (int nt = 0; nt < 8; ++nt) {
        const int j = j0 + nt * 16 + ln15;
        #pragma unroll
        for (int r = 0; r < 4; ++r) {
            const int i = i0w + quad * 4 + r;
            const float bvv = bgb[(size_t)i * NTOK + j];
            const int mv = adj[i * NTOK + j];
            s[nt][r] += (mv > 0) ? bvv : NEG_INF;
        }
    }

    // ---- single-tile softmax stats ----
    float p[8][4], m_r[4], l_r[4];
    #pragma unroll
    for (int r = 0; r < 4; ++r) {
        float mx = s[0][r];
        #pragma unroll
        for (int nt = 1; nt < 8; ++nt) mx = fmaxf(mx, s[nt][r]);
        #pragma unroll
        for (int off = 1; off < 16; off <<= 1) mx = fmaxf(mx, __shfl_xor(mx, off, 64));
        float rs = 0.f;
        #pragma unroll
        for (int nt = 0; nt < 8; ++nt) { p[nt][r] = __expf(s[nt][r] - mx); rs += p[nt][r]; }
        #pragma unroll
        for (int off = 1; off < 16; off <<= 1) rs += __shfl_xor(rs, off, 64);
        m_r[r] = mx; l_r[r] = rs;
    }

    // ---- P -> per-wave LDS (C-layout scatter), read back as A-frags ----
    #pragma unroll
    for (int nt = 0; nt < 8; ++nt)
        #pragma unroll
        for (int r = 0; r < 4; ++r)
            Pl[w][(quad * 4 + r) * PL_STRIDE + nt * 16 + ln15] = f2bf(p[nt][r]);

    bf16x8 ap[4];
    #pragma unroll
    for (int kt = 0; kt < 4; ++kt)
        ap[kt] = *(const bf16x8*)&Pl[w][ln15 * PL_STRIDE + kt * 32 + quad * 8];

    // ---- O_partial = P V (unnormalized) ----
    f32x4 o_acc[4];
    #pragma unroll
    for (int dt = 0; dt < 4; ++dt) o_acc[dt] = (f32x4){0.f, 0.f, 0.f, 0.f};
    #pragma unroll
    for (int dt = 0; dt < 4; ++dt) {
        #pragma unroll
        for (int kt = 0; kt < 4; ++kt) {
            bf16x8 bv;
            #pragma unroll
            for (int jj = 0; jj < 8; ++jj)
                bv[jj] = Vn[(kt * 32 + quad * 8 + jj) * VN_STRIDE + dt * 16 + ln15];
            o_acc[dt] = __builtin_amdgcn_mfma_f32_16x16x32_bf16(ap[kt], bv, o_acc[dt], 0, 0, 0);
        }
    }

    // ---- write partials ----
    #pragma unroll
    for (int dt = 0; dt < 4; ++dt)
        #pragma unroll
        for (int r = 0; r < 4; ++r) {
            const int i = i0w + quad * 4 + r;
            Opart[((size_t)(b * NTOK) + i) * HID + h * HD + dt * 16 + ln15] = o_acc[dt][r];
        }
    if (ln15 == 0) {
        #pragma unroll
        for (int r = 0; r < 4; ++r) {
            const int i = i0w + quad * 4 + r;
            float* mlp = mlbuf + (((size_t)(js * BATCH + b) * NTOK + i) * HEADS + h) * 2;
            mlp[0] = m_r[r]; mlp[1] = l_r[r];
        }
    }
}

// ---------------------------------------------------------------------------
// Stage D: merge attention partials (flash-decode combine) + out = O@Wo + bo
// ---------------------------------------------------------------------------
__global__ __launch_bounds__(256) void pga_outproj(
    const float* __restrict__ op0, const float* __restrict__ op1,
    const float* __restrict__ op2, const float* __restrict__ op3,
    const float* __restrict__ mlbuf,
    const float* __restrict__ Wo, const float* __restrict__ bo,
    float* __restrict__ out)
{
    __shared__ float xs[16][HID];
    const int m0 = blockIdx.x * 16;
    const int t = threadIdx.x;
    const int c = t;
    const int h = c >> 6;

    const float* ops[4] = {op0, op1, op2, op3};

    #pragma unroll 4
    for (int r = 0; r < 16; ++r) {
        const int ig = m0 + r;
        const int b = ig >> 9, i = ig & 511;
        float po[4], ms[4], ls[4];
        #pragma unroll
        for (int s = 0; s < 4; ++s) {
            po[s] = ops[s][(size_t)ig * HID + c];
            const float* mlp = mlbuf + (((size_t)(s * BATCH + b) * NTOK + i) * HEADS + h) * 2;
            ms[s] = mlp[0]; ls[s] = mlp[1];
        }
        const float mmax = fmaxf(fmaxf(ms[0], ms[1]), fmaxf(ms[2], ms[3]));
        float L = 0.f, val = 0.f;
        #pragma unroll
        for (int s = 0; s < 4; ++s) {
            const float e = __expf(ms[s] - mmax);
            L += ls[s] * e;
            val = fmaf(po[s], e, val);
        }
        xs[r][c] = val / L;
    }
    __syncthreads();

    const int cg = t & 63;
    const int rg = t >> 6;
    const float4 bias4 = ((const float4*)bo)[cg];
    float4 acc[4] = {bias4, bias4, bias4, bias4};

    const float4* W4 = (const float4*)Wo;
    for (int kq = 0; kq < 64; ++kq) {
        const float4 w0 = W4[(4 * kq + 0) * 64 + cg];
        const float4 w1 = W4[(4 * kq + 1) * 64 + cg];
        const float4 w2 = W4[(4 * kq + 2) * 64 + cg];
        const float4 w3 = W4[(4 * kq + 3) * 64 + cg];
        #pragma unroll
        for (int r = 0; r < 4; ++r) {
            const float4 xv = ((const float4*)xs[4 * rg + r])[kq];
            acc[r].x = fmaf(xv.x, w0.x, fmaf(xv.y, w1.x, fmaf(xv.z, w2.x, fmaf(xv.w, w3.x, acc[r].x))));
            acc[r].y = fmaf(xv.x, w0.y, fmaf(xv.y, w1.y, fmaf(xv.z, w2.y, fmaf(xv.w, w3.y, acc[r].y))));
            acc[r].z = fmaf(xv.x, w0.z, fmaf(xv.y, w1.z, fmaf(xv.z, w2.z, fmaf(xv.w, w3.z, acc[r].z))));
            acc[r].w = fmaf(xv.x, w0.w, fmaf(xv.y, w1.w, fmaf(xv.z, w2.w, fmaf(xv.w, w3.w, acc[r].w))));
        }
    }
    #pragma unroll
    for (int r = 0; r < 4; ++r)
        ((float4*)(out + (m0 + 4 * rg + r) * HID))[cg] = acc[r];
}

extern "C" void kernel_launch(void* const* d_in, const int* in_sizes, int n_in,
                              void* d_out, int out_size, void* d_ws, size_t ws_size,
                              hipStream_t stream) {
    const float* x   = (const float*)d_in[0];
    const int*   adj = (const int*)d_in[1];
    const float* Wq  = (const float*)d_in[2];
    const float* bq  = (const float*)d_in[3];
    const float* Wk  = (const float*)d_in[4];
    const float* bk  = (const float*)d_in[5];
    const float* Wv  = (const float*)d_in[6];
    const float* bv  = (const float*)d_in[7];
    const float* Wo  = (const float*)d_in[8];
    const float* bo  = (const float*)d_in[9];
    const float* Wp1 = (const float*)d_in[10];
    const float* bp1 = (const float*)d_in[11];
    const float* Wp2 = (const float*)d_in[12];
    const float* bp2 = (const float*)d_in[13];
    float* out = (float*)d_out;

    // ws layout (floats), ~15.9 MB total. A/BbT die after pga_bias and are
    // reused as Opart[0]/Opart[1] by pga_attn (same-stream ordering).
    float* ws   = (float*)d_ws;
    float* Q    = ws;
    float* K    = ws + 262144;
    float* V    = ws + 2 * 262144;
    float* A    = ws + 3 * 262144;     // -> Opart[0]
    float* BbT  = ws + 4 * 262144;     // -> Opart[1]
    float* bias = ws + 5 * 262144;     // 2097152 floats
    float* Op2  = ws + 5 * 262144 + 2097152;
    float* Op3  = Op2 + 262144;
    float* mlb  = Op3 + 262144;        // 32768 floats

    pga_proj5<<<dim3(64, 5), 256, 0, stream>>>(x, Wq, bq, Wk, bk, Wv, bv,
                                               Wp1, bp1, Q, K, V, A, BbT);
    pga_bias<<<512, 576, 0, stream>>>(A, BbT, Wp2, bp2, adj, bias);
    pga_attn<<<256, 256, 0, stream>>>(Q, K, V, bias, adj, A, BbT, Op2, Op3, mlb);
    pga_outproj<<<64, 256, 0, stream>>>(A, BbT, Op2, Op3, mlb, Wo, bo, out);
}

// Round 8
// 178.896 us; speedup vs baseline: 1.5703x; 1.1762x over previous
//
#include <hip/hip_runtime.h>
#include <hip/hip_bf16.h>
#include <math.h>

#define NTOK 512      // N
#define BATCH 2
#define HID 256
#define HEADS 4
#define HD 64
#define NEG_INF -1e9f

typedef short bf16x8 __attribute__((ext_vector_type(8)));
typedef short bf16x4 __attribute__((ext_vector_type(4)));
typedef float f32x4 __attribute__((ext_vector_type(4)));

__device__ __forceinline__ short f2bf(float f) {
    union { __hip_bfloat16 h; short s; } u;
    u.h = __float2bfloat16(f);
    return u.s;
}

// Branch-free gelu via A&S 7.1.26 erf (max erf err 1.5e-7), exp2-based,
// poly coeffs pre-scaled by 0.5.
__device__ __forceinline__ float fast_gelu(float x) {
    const float z = fabsf(x) * 0.70710678118654752f;
    const float t = __builtin_amdgcn_rcpf(fmaf(0.3275911f, z, 1.0f));
    float p = fmaf(0.530702714f, t, -0.726576013f);
    p = fmaf(p, t, 0.710706871f);
    p = fmaf(p, t, -0.142248368f);
    p = fmaf(p, t, 0.127414796f);
    p = p * t;
    const float E = __builtin_amdgcn_exp2f(z * z * -1.44269504088896f);
    const float phin = p * E;                         // Phi(-|x|) in [0,0.5]
    const float phi = 0.5f + copysignf(0.5f - phin, x);
    return x * phi;
}

// ---------------------------------------------------------------------------
// Stage A: fused 5-way projection GEMM.  Y = X @ W (+bias)
// ---------------------------------------------------------------------------
__global__ __launch_bounds__(256) void pga_proj5(
    const float* __restrict__ x,
    const float* __restrict__ Wq, const float* __restrict__ bq,
    const float* __restrict__ Wk, const float* __restrict__ bk,
    const float* __restrict__ Wv, const float* __restrict__ bv,
    const float* __restrict__ Wp1, const float* __restrict__ bp1,
    float* __restrict__ Q, float* __restrict__ K, float* __restrict__ V,
    float* __restrict__ A, float* __restrict__ BbT)
{
    __shared__ float xs[16][HID];
    const int m0 = blockIdx.x * 16;
    const int which = blockIdx.y;
    const int t = threadIdx.x;
    const int cg = t & 63;
    const int rg = t >> 6;

    {
        const float4* xg = (const float4*)(x + m0 * HID);
        float4* xsv = (float4*)xs;
        #pragma unroll
        for (int k = 0; k < 4; ++k) xsv[t + 256 * k] = xg[t + 256 * k];
    }
    __syncthreads();

    const float* W; const float* bvec; float* out; bool transposed = false;
    switch (which) {
        case 0: W = Wq; bvec = bq; out = Q; break;
        case 1: W = Wk; bvec = bk; out = K; break;
        case 2: W = Wv; bvec = bv; out = V; break;
        case 3: W = Wp1; bvec = bp1; out = A; break;
        default: W = Wp1 + HID * HID; bvec = nullptr; out = BbT; transposed = true; break;
    }

    float4 bias4 = make_float4(0.f, 0.f, 0.f, 0.f);
    if (bvec) bias4 = ((const float4*)bvec)[cg];
    float4 acc[4] = {bias4, bias4, bias4, bias4};

    const float4* W4 = (const float4*)W;
    for (int kq = 0; kq < 64; ++kq) {
        const float4 w0 = W4[(4 * kq + 0) * 64 + cg];
        const float4 w1 = W4[(4 * kq + 1) * 64 + cg];
        const float4 w2 = W4[(4 * kq + 2) * 64 + cg];
        const float4 w3 = W4[(4 * kq + 3) * 64 + cg];
        #pragma unroll
        for (int r = 0; r < 4; ++r) {
            const float4 xv = ((const float4*)xs[4 * rg + r])[kq];
            acc[r].x = fmaf(xv.x, w0.x, fmaf(xv.y, w1.x, fmaf(xv.z, w2.x, fmaf(xv.w, w3.x, acc[r].x))));
            acc[r].y = fmaf(xv.x, w0.y, fmaf(xv.y, w1.y, fmaf(xv.z, w2.y, fmaf(xv.w, w3.y, acc[r].y))));
            acc[r].z = fmaf(xv.x, w0.z, fmaf(xv.y, w1.z, fmaf(xv.z, w2.z, fmaf(xv.w, w3.z, acc[r].z))));
            acc[r].w = fmaf(xv.x, w0.w, fmaf(xv.y, w1.w, fmaf(xv.z, w2.w, fmaf(xv.w, w3.w, acc[r].w))));
        }
    }

    if (!transposed) {
        #pragma unroll
        for (int r = 0; r < 4; ++r)
            ((float4*)(out + (m0 + 4 * rg + r) * HID))[cg] = acc[r];
    } else {
        const int b = m0 >= NTOK;
        const int n0 = m0 - b * NTOK;
        #pragma unroll
        for (int r = 0; r < 4; ++r) {
            const int row = n0 + 4 * rg + r;
            float* ob = BbT + b * (HID * NTOK);
            ob[(4 * cg + 0) * NTOK + row] = acc[r].x;
            ob[(4 * cg + 1) * NTOK + row] = acc[r].y;
            ob[(4 * cg + 2) * NTOK + row] = acc[r].z;
            ob[(4 * cg + 3) * NTOK + row] = acc[r].w;
        }
    }
}

// ---------------------------------------------------------------------------
// Stage B: physics bias over valid pairs. Two rows per block, self-compacted
//   into LDS. 576 threads (9 waves): ct ~ 512+-16 -> single pass.
// ---------------------------------------------------------------------------
__global__ __launch_bounds__(576) void pga_bias(
    const float* __restrict__ A, const float* __restrict__ BbT,
    const float* __restrict__ Wp2, const float* __restrict__ bp2,
    const int* __restrict__ adj, float* __restrict__ biasg)
{
    __shared__ float as[2][HID];
    __shared__ float4 wp[HID];
    __shared__ short jlist[2][NTOK];
    __shared__ int wcnt[2][9];

    const int t = threadIdx.x;          // 0..575
    const int b = blockIdx.x >> 8;
    const int i0 = (blockIdx.x & 255) * 2;
    const int w = t >> 6, lane = t & 63;
    const unsigned long long ltm = (1ull << lane) - 1ull;

    if (t < 2 * HID) as[t >> 8][t & 255] = A[(b * NTOK + i0 + (t >> 8)) * HID + (t & 255)];
    if (t < HID) wp[t] = ((const float4*)Wp2)[t];

    // ---- ordered ballot compaction of rows i0, i0+1 (j = t for t<512) ----
    bool m0 = false, m1 = false;
    if (t < NTOK) {
        m0 = adj[(i0 + 0) * NTOK + t] > 0;
        m1 = adj[(i0 + 1) * NTOK + t] > 0;
    }
    const unsigned long long bm0 = __ballot(m0);
    const unsigned long long bm1 = __ballot(m1);
    if (lane == 0) { wcnt[0][w] = __popcll(bm0); wcnt[1][w] = __popcll(bm1); }
    __syncthreads();
    int base0 = 0, base1 = 0, tot0 = 0, tot1 = 0;
    #pragma unroll
    for (int w2 = 0; w2 < 9; ++w2) {
        const int c0 = wcnt[0][w2], c1 = wcnt[1][w2];
        if (w2 < w) { base0 += c0; base1 += c1; }
        tot0 += c0; tot1 += c1;
    }
    if (m0) jlist[0][base0 + __popcll(bm0 & ltm)] = (short)t;
    if (m1) jlist[1][base1 + __popcll(bm1 & ltm)] = (short)t;
    __syncthreads();

    // ---- main: one valid pair per lane (single pass in practice) ----
    const int ct = tot0 + tot1;
    const float* bb = BbT + b * (HID * NTOK);
    const float4 bp = *(const float4*)bp2;

    for (int idx = t; idx < ct; idx += 576) {
        const int r = idx >= tot0;
        const int j = jlist[r][idx - (r ? tot0 : 0)];
        const float* asr = as[r];
        float ah0 = 0.f, ah1 = 0.f, ah2 = 0.f, ah3 = 0.f;
        #pragma unroll 4
        for (int d = 0; d < HID; ++d) {
            const float g = fast_gelu(asr[d] + bb[d * NTOK + j]);
            const float4 wv = wp[d];
            ah0 = fmaf(g, wv.x, ah0); ah1 = fmaf(g, wv.y, ah1);
            ah2 = fmaf(g, wv.z, ah2); ah3 = fmaf(g, wv.w, ah3);
        }
        const int i = i0 + r;
        float* o = biasg + (((size_t)b * HEADS) * NTOK + i) * NTOK + j;
        o[0 * NTOK * NTOK] = ah0 + bp.x;
        o[1 * NTOK * NTOK] = ah1 + bp.y;
        o[2 * NTOK * NTOK] = ah2 + bp.z;
        o[3 * NTOK * NTOK] = ah3 + bp.w;
    }
}

// ---------------------------------------------------------------------------
// Stage C: MFMA attention, flash-decoding j-split. grid = 256 blocks =
//   (b, h, qt, js): each block does ONE 128-j tile for 64 q-rows, writing
//   unnormalized O-partial + per-row (m, l). Merge happens in pga_outproj.
// ---------------------------------------------------------------------------
#define KT_STRIDE 72
#define VN_STRIDE 76
#define PL_STRIDE 136

__global__ __launch_bounds__(256) void pga_attn(
    const float* __restrict__ Q, const float* __restrict__ K,
    const float* __restrict__ V, const float* __restrict__ biasg,
    const int* __restrict__ adj,
    float* __restrict__ op0, float* __restrict__ op1,
    float* __restrict__ op2, float* __restrict__ op3,
    float* __restrict__ mlbuf)
{
    __shared__ short Kt[128 * KT_STRIDE];
    __shared__ short Vn[128 * VN_STRIDE];
    __shared__ short Pl[4][16 * PL_STRIDE];

    const int blk = blockIdx.x;
    const int js = blk & 3;
    const int qt = (blk >> 2) & 7;
    const int h  = (blk >> 5) & 3;
    const int b  = blk >> 7;
    const int t = threadIdx.x;
    const int w = t >> 6;
    const int lane = t & 63;
    const int ln15 = lane & 15;
    const int quad = lane >> 4;

    float* Opart = (js == 0) ? op0 : (js == 1) ? op1 : (js == 2) ? op2 : op3;
    const int j0 = js * 128;
    const int i0w = qt * 64 + w * 16;

    // ---- Q A-fragments (scale folded into bf16 conversion) ----
    bf16x8 aq0, aq1;
    {
        const float* qrow = Q + ((size_t)(b * NTOK) + i0w + ln15) * HID + h * HD;
        const int k0 = quad * 8;
        #pragma unroll
        for (int jj = 0; jj < 8; ++jj) {
            aq0[jj] = f2bf(qrow[k0 + jj] * 0.125f);
            aq1[jj] = f2bf(qrow[32 + k0 + jj] * 0.125f);
        }
    }

    // ---- stage K,V tile ----
    for (int k = 0; k < 8; ++k) {
        const int flat4 = k * 256 + t;
        const int jl = flat4 >> 4, dq = flat4 & 15;
        const float4 kv = ((const float4*)(K + ((size_t)(b * NTOK) + j0 + jl) * HID + h * HD))[dq];
        const float4 vv = ((const float4*)(V + ((size_t)(b * NTOK) + j0 + jl) * HID + h * HD))[dq];
        bf16x4 ks, vs;
        ks[0] = f2bf(kv.x); ks[1] = f2bf(kv.y); ks[2] = f2bf(kv.z); ks[3] = f2bf(kv.w);
        vs[0] = f2bf(vv.x); vs[1] = f2bf(vv.y); vs[2] = f2bf(vv.z); vs[3] = f2bf(vv.w);
        *(bf16x4*)&Kt[jl * KT_STRIDE + dq * 4] = ks;
        *(bf16x4*)&Vn[jl * VN_STRIDE + dq * 4] = vs;
    }
    __syncthreads();

    // ---- S = Q K^T ----
    f32x4 s[8];
    #pragma unroll
    for (int nt = 0; nt < 8; ++nt) {
        const int krow = nt * 16 + ln15;
        const bf16x8 bk0 = *(const bf16x8*)&Kt[krow * KT_STRIDE + quad * 8];
        const bf16x8 bk1 = *(const bf16x8*)&Kt[krow * KT_STRIDE + 32 + quad * 8];
        f32x4 acc = (f32x4){0.f, 0.f, 0.f, 0.f};
        acc = __builtin_amdgcn_mfma_f32_16x16x32_bf16(aq0, bk0, acc, 0, 0, 0);
        acc = __builtin_amdgcn_mfma_f32_16x16x32_bf16(aq1, bk1, acc, 0, 0, 0);
        s[nt] = acc;
    }

    // ---- add masked bias ----
    const float* bgb = biasg + ((size_t)(b * HEADS + h)) * NTOK * NTOK;
    #pragma unroll
    for (int nt = 0; nt < 8; ++nt) {
        const int j = j0 + nt * 16 + ln15;
        #pragma unroll
        for (int r = 0; r < 4; ++r) {
            const int i = i0w + quad * 4 + r;
            const float bvv = bgb[(size_t)i * NTOK + j];
            const int mv = adj[i * NTOK + j];
            s[nt][r] += (mv > 0) ? bvv : NEG_INF;
        }
    }

    // ---- single-tile softmax stats ----
    float p[8][4], m_r[4], l_r[4];
    #pragma unroll
    for (int r = 0; r < 4; ++r) {
        float mx = s[0][r];
        #pragma unroll
        for (int nt = 1; nt < 8; ++nt) mx = fmaxf(mx, s[nt][r]);
        #pragma unroll
        for (int off = 1; off < 16; off <<= 1) mx = fmaxf(mx, __shfl_xor(mx, off, 64));
        float rs = 0.f;
        #pragma unroll
        for (int nt = 0; nt < 8; ++nt) { p[nt][r] = __expf(s[nt][r] - mx); rs += p[nt][r]; }
        #pragma unroll
        for (int off = 1; off < 16; off <<= 1) rs += __shfl_xor(rs, off, 64);
        m_r[r] = mx; l_r[r] = rs;
    }

    // ---- P -> per-wave LDS (C-layout scatter), read back as A-frags ----
    #pragma unroll
    for (int nt = 0; nt < 8; ++nt)
        #pragma unroll
        for (int r = 0; r < 4; ++r)
            Pl[w][(quad * 4 + r) * PL_STRIDE + nt * 16 + ln15] = f2bf(p[nt][r]);

    bf16x8 ap[4];
    #pragma unroll
    for (int kt = 0; kt < 4; ++kt)
        ap[kt] = *(const bf16x8*)&Pl[w][ln15 * PL_STRIDE + kt * 32 + quad * 8];

    // ---- O_partial = P V (unnormalized) ----
    f32x4 o_acc[4];
    #pragma unroll
    for (int dt = 0; dt < 4; ++dt) o_acc[dt] = (f32x4){0.f, 0.f, 0.f, 0.f};
    #pragma unroll
    for (int dt = 0; dt < 4; ++dt) {
        #pragma unroll
        for (int kt = 0; kt < 4; ++kt) {
            bf16x8 bv;
            #pragma unroll
            for (int jj = 0; jj < 8; ++jj)
                bv[jj] = Vn[(kt * 32 + quad * 8 + jj) * VN_STRIDE + dt * 16 + ln15];
            o_acc[dt] = __builtin_amdgcn_mfma_f32_16x16x32_bf16(ap[kt], bv, o_acc[dt], 0, 0, 0);
        }
    }

    // ---- write partials ----
    #pragma unroll
    for (int dt = 0; dt < 4; ++dt)
        #pragma unroll
        for (int r = 0; r < 4; ++r) {
            const int i = i0w + quad * 4 + r;
            Opart[((size_t)(b * NTOK) + i) * HID + h * HD + dt * 16 + ln15] = o_acc[dt][r];
        }
    if (ln15 == 0) {
        #pragma unroll
        for (int r = 0; r < 4; ++r) {
            const int i = i0w + quad * 4 + r;
            float* mlp = mlbuf + (((size_t)(js * BATCH + b) * NTOK + i) * HEADS + h) * 2;
            mlp[0] = m_r[r]; mlp[1] = l_r[r];
        }
    }
}

// ---------------------------------------------------------------------------
// Stage D: merge attention partials + out = O@Wo + bo.
//   256 blocks x 4 rows (1 block/CU): latency hidden by device-wide TLP.
// ---------------------------------------------------------------------------
__global__ __launch_bounds__(256) void pga_outproj(
    const float* __restrict__ op0, const float* __restrict__ op1,
    const float* __restrict__ op2, const float* __restrict__ op3,
    const float* __restrict__ mlbuf,
    const float* __restrict__ Wo, const float* __restrict__ bo,
    float* __restrict__ out)
{
    __shared__ float xs[4][HID];
    const int m0 = blockIdx.x * 4;
    const int t = threadIdx.x;
    const int c = t;                  // col for merge phase
    const int h = c >> 6;

    const float* ops[4] = {op0, op1, op2, op3};

    #pragma unroll
    for (int r = 0; r < 4; ++r) {
        const int ig = m0 + r;
        const int b = ig >> 9, i = ig & 511;
        float po[4], ms[4], ls[4];
        #pragma unroll
        for (int s = 0; s < 4; ++s) {
            po[s] = ops[s][(size_t)ig * HID + c];
            const float* mlp = mlbuf + (((size_t)(s * BATCH + b) * NTOK + i) * HEADS + h) * 2;
            ms[s] = mlp[0]; ls[s] = mlp[1];
        }
        const float mmax = fmaxf(fmaxf(ms[0], ms[1]), fmaxf(ms[2], ms[3]));
        float L = 0.f, val = 0.f;
        #pragma unroll
        for (int s = 0; s < 4; ++s) {
            const float e = __expf(ms[s] - mmax);
            L += ls[s] * e;
            val = fmaf(po[s], e, val);
        }
        xs[r][c] = val / L;
    }
    __syncthreads();

    const int cg = t & 63;
    const int rg = t >> 6;            // each thread: 1 row x 4 cols
    float4 acc = ((const float4*)bo)[cg];

    const float4* W4 = (const float4*)Wo;
    const float4* xrow = (const float4*)xs[rg];
    #pragma unroll 2
    for (int kq = 0; kq < 64; ++kq) {
        const float4 w0 = W4[(4 * kq + 0) * 64 + cg];
        const float4 w1 = W4[(4 * kq + 1) * 64 + cg];
        const float4 w2 = W4[(4 * kq + 2) * 64 + cg];
        const float4 w3 = W4[(4 * kq + 3) * 64 + cg];
        const float4 xv = xrow[kq];
        acc.x = fmaf(xv.x, w0.x, fmaf(xv.y, w1.x, fmaf(xv.z, w2.x, fmaf(xv.w, w3.x, acc.x))));
        acc.y = fmaf(xv.x, w0.y, fmaf(xv.y, w1.y, fmaf(xv.z, w2.y, fmaf(xv.w, w3.y, acc.y))));
        acc.z = fmaf(xv.x, w0.z, fmaf(xv.y, w1.z, fmaf(xv.z, w2.z, fmaf(xv.w, w3.z, acc.z))));
        acc.w = fmaf(xv.x, w0.w, fmaf(xv.y, w1.w, fmaf(xv.z, w2.w, fmaf(xv.w, w3.w, acc.w))));
    }
    ((float4*)(out + (m0 + rg) * HID))[cg] = acc;
}

extern "C" void kernel_launch(void* const* d_in, const int* in_sizes, int n_in,
                              void* d_out, int out_size, void* d_ws, size_t ws_size,
                              hipStream_t stream) {
    const float* x   = (const float*)d_in[0];
    const int*   adj = (const int*)d_in[1];
    const float* Wq  = (const float*)d_in[2];
    const float* bq  = (const float*)d_in[3];
    const float* Wk  = (const float*)d_in[4];
    const float* bk  = (const float*)d_in[5];
    const float* Wv  = (const float*)d_in[6];
    const float* bv  = (const float*)d_in[7];
    const float* Wo  = (const float*)d_in[8];
    const float* bo  = (const float*)d_in[9];
    const float* Wp1 = (const float*)d_in[10];
    const float* bp1 = (const float*)d_in[11];
    const float* Wp2 = (const float*)d_in[12];
    const float* bp2 = (const float*)d_in[13];
    float* out = (float*)d_out;

    // ws layout (floats), ~15.9 MB total. A/BbT die after pga_bias and are
    // reused as Opart[0]/Opart[1] by pga_attn (same-stream ordering).
    float* ws   = (float*)d_ws;
    float* Q    = ws;
    float* K    = ws + 262144;
    float* V    = ws + 2 * 262144;
    float* A    = ws + 3 * 262144;     // -> Opart[0]
    float* BbT  = ws + 4 * 262144;     // -> Opart[1]
    float* bias = ws + 5 * 262144;     // 2097152 floats
    float* Op2  = ws + 5 * 262144 + 2097152;
    float* Op3  = Op2 + 262144;
    float* mlb  = Op3 + 262144;        // 32768 floats

    pga_proj5<<<dim3(64, 5), 256, 0, stream>>>(x, Wq, bq, Wk, bk, Wv, bv,
                                               Wp1, bp1, Q, K, V, A, BbT);
    pga_bias<<<512, 576, 0, stream>>>(A, BbT, Wp2, bp2, adj, bias);
    pga_attn<<<256, 256, 0, stream>>>(Q, K, V, bias, adj, A, BbT, Op2, Op3, mlb);
    pga_outproj<<<256, 256, 0, stream>>>(A, BbT, Op2, Op3, mlb, Wo, bo, out);
}

// Round 9
// 164.685 us; speedup vs baseline: 1.7058x; 1.0863x over previous
//
#include <hip/hip_runtime.h>
#include <hip/hip_bf16.h>
#include <math.h>

#define NTOK 512      // N
#define BATCH 2
#define HID 256
#define HEADS 4
#define HD 64
#define NEG_INF -1e9f

typedef short bf16x8 __attribute__((ext_vector_type(8)));
typedef short bf16x4 __attribute__((ext_vector_type(4)));
typedef float f32x4 __attribute__((ext_vector_type(4)));

__device__ __forceinline__ short f2bf(float f) {
    union { __hip_bfloat16 h; short s; } u;
    u.h = __float2bfloat16(f);
    return u.s;
}

// tanh-form gelu, exp2+rcp based (8 ops, 2 trans):
//   gelu(x) = 0.5x(1+tanh(0.79788456(x+0.044715x^3)))
//           = x - x * rcp(exp2(2.3021176 * x * (1+0.044715x^2)) + 1)
// Saturates correctly for |x| large (exp2->inf => rcp->0 => gelu->x).
__device__ __forceinline__ float fast_gelu(float x) {
    const float x2 = x * x;
    const float u = x * fmaf(x2, 0.044715f, 1.0f);
    const float e = __builtin_amdgcn_exp2f(u * 2.3021176f);
    const float r = __builtin_amdgcn_rcpf(e + 1.0f);
    return fmaf(-x, r, x);
}

// ---------------------------------------------------------------------------
// Stage A: fused 5-way projection GEMM.  Y = X @ W (+bias)
// ---------------------------------------------------------------------------
__global__ __launch_bounds__(256) void pga_proj5(
    const float* __restrict__ x,
    const float* __restrict__ Wq, const float* __restrict__ bq,
    const float* __restrict__ Wk, const float* __restrict__ bk,
    const float* __restrict__ Wv, const float* __restrict__ bv,
    const float* __restrict__ Wp1, const float* __restrict__ bp1,
    float* __restrict__ Q, float* __restrict__ K, float* __restrict__ V,
    float* __restrict__ A, float* __restrict__ BbT)
{
    __shared__ float xs[16][HID];
    const int m0 = blockIdx.x * 16;
    const int which = blockIdx.y;
    const int t = threadIdx.x;
    const int cg = t & 63;
    const int rg = t >> 6;

    {
        const float4* xg = (const float4*)(x + m0 * HID);
        float4* xsv = (float4*)xs;
        #pragma unroll
        for (int k = 0; k < 4; ++k) xsv[t + 256 * k] = xg[t + 256 * k];
    }
    __syncthreads();

    const float* W; const float* bvec; float* out; bool transposed = false;
    switch (which) {
        case 0: W = Wq; bvec = bq; out = Q; break;
        case 1: W = Wk; bvec = bk; out = K; break;
        case 2: W = Wv; bvec = bv; out = V; break;
        case 3: W = Wp1; bvec = bp1; out = A; break;
        default: W = Wp1 + HID * HID; bvec = nullptr; out = BbT; transposed = true; break;
    }

    float4 bias4 = make_float4(0.f, 0.f, 0.f, 0.f);
    if (bvec) bias4 = ((const float4*)bvec)[cg];
    float4 acc[4] = {bias4, bias4, bias4, bias4};

    const float4* W4 = (const float4*)W;
    for (int kq = 0; kq < 64; ++kq) {
        const float4 w0 = W4[(4 * kq + 0) * 64 + cg];
        const float4 w1 = W4[(4 * kq + 1) * 64 + cg];
        const float4 w2 = W4[(4 * kq + 2) * 64 + cg];
        const float4 w3 = W4[(4 * kq + 3) * 64 + cg];
        #pragma unroll
        for (int r = 0; r < 4; ++r) {
            const float4 xv = ((const float4*)xs[4 * rg + r])[kq];
            acc[r].x = fmaf(xv.x, w0.x, fmaf(xv.y, w1.x, fmaf(xv.z, w2.x, fmaf(xv.w, w3.x, acc[r].x))));
            acc[r].y = fmaf(xv.x, w0.y, fmaf(xv.y, w1.y, fmaf(xv.z, w2.y, fmaf(xv.w, w3.y, acc[r].y))));
            acc[r].z = fmaf(xv.x, w0.z, fmaf(xv.y, w1.z, fmaf(xv.z, w2.z, fmaf(xv.w, w3.z, acc[r].z))));
            acc[r].w = fmaf(xv.x, w0.w, fmaf(xv.y, w1.w, fmaf(xv.z, w2.w, fmaf(xv.w, w3.w, acc[r].w))));
        }
    }

    if (!transposed) {
        #pragma unroll
        for (int r = 0; r < 4; ++r)
            ((float4*)(out + (m0 + 4 * rg + r) * HID))[cg] = acc[r];
    } else {
        const int b = m0 >= NTOK;
        const int n0 = m0 - b * NTOK;
        #pragma unroll
        for (int r = 0; r < 4; ++r) {
            const int row = n0 + 4 * rg + r;
            float* ob = BbT + b * (HID * NTOK);
            ob[(4 * cg + 0) * NTOK + row] = acc[r].x;
            ob[(4 * cg + 1) * NTOK + row] = acc[r].y;
            ob[(4 * cg + 2) * NTOK + row] = acc[r].z;
            ob[(4 * cg + 3) * NTOK + row] = acc[r].w;
        }
    }
}

// ---------------------------------------------------------------------------
// Stage B: physics bias over valid pairs. ONE row per 320-thread block
//   (5 waves). Row count ~ 256+-11 < 320 -> guaranteed single pass, and
//   5-wave blocks pack ~6/CU = 30 waves/CU for latency hiding.
//   Compaction: waves 0..4 own 64-j chunks {w, w+5} (chunks 5..7 on waves
//   0..2), ordered prefix over per-chunk counts keeps ascending-j order.
// ---------------------------------------------------------------------------
__global__ __launch_bounds__(320) void pga_bias(
    const float* __restrict__ A, const float* __restrict__ BbT,
    const float* __restrict__ Wp2, const float* __restrict__ bp2,
    const int* __restrict__ adj, float* __restrict__ biasg)
{
    __shared__ float as[HID];
    __shared__ float4 wp[HID];
    __shared__ short jlist[NTOK];
    __shared__ int ccnt[8];

    const int t = threadIdx.x;          // 0..319
    const int b = blockIdx.x >> 9;
    const int i = blockIdx.x & 511;
    const int w = t >> 6, lane = t & 63;
    const unsigned long long ltm = (1ull << lane) - 1ull;

    if (t < HID) {
        as[t] = A[(b * NTOK + i) * HID + t];
        wp[t] = ((const float4*)Wp2)[t];
    }

    // ---- ordered ballot compaction of row i ----
    const int c0 = w, c1 = w + 5;       // chunk ids for this wave (c1<8 only w<3)
    bool m0 = adj[i * NTOK + c0 * 64 + lane] > 0;
    bool m1 = (c1 < 8) ? (adj[i * NTOK + c1 * 64 + lane] > 0) : false;
    const unsigned long long bm0 = __ballot(m0);
    const unsigned long long bm1 = __ballot(m1);
    if (lane == 0) {
        ccnt[c0] = __popcll(bm0);
        if (c1 < 8) ccnt[c1] = __popcll(bm1);
    }
    __syncthreads();

    int pref0 = 0, pref1 = 0, tot = 0;
    #pragma unroll
    for (int c = 0; c < 8; ++c) {
        if (c == c0) pref0 = tot;
        if (c == c1) pref1 = tot;
        tot += ccnt[c];
    }
    if (m0) jlist[pref0 + __popcll(bm0 & ltm)] = (short)(c0 * 64 + lane);
    if (c1 < 8 && m1) jlist[pref1 + __popcll(bm1 & ltm)] = (short)(c1 * 64 + lane);
    __syncthreads();

    // ---- main: one valid pair per lane, single pass (tot <= 320 w.h.p.) ----
    const float* bb = BbT + b * (HID * NTOK);
    const float4 bp = *(const float4*)bp2;

    for (int idx = t; idx < tot; idx += 320) {
        const int j = jlist[idx];
        float ah0 = 0.f, ah1 = 0.f, ah2 = 0.f, ah3 = 0.f;
        #pragma unroll 4
        for (int d = 0; d < HID; ++d) {
            const float g = fast_gelu(as[d] + bb[d * NTOK + j]);
            const float4 wv = wp[d];
            ah0 = fmaf(g, wv.x, ah0); ah1 = fmaf(g, wv.y, ah1);
            ah2 = fmaf(g, wv.z, ah2); ah3 = fmaf(g, wv.w, ah3);
        }
        float* o = biasg + (((size_t)b * HEADS) * NTOK + i) * NTOK + j;
        o[0 * NTOK * NTOK] = ah0 + bp.x;
        o[1 * NTOK * NTOK] = ah1 + bp.y;
        o[2 * NTOK * NTOK] = ah2 + bp.z;
        o[3 * NTOK * NTOK] = ah3 + bp.w;
    }
}

// ---------------------------------------------------------------------------
// Stage C: MFMA attention, flash-decoding j-split. grid = 256 blocks =
//   (b, h, qt, js): each block does ONE 128-j tile for 64 q-rows, writing
//   unnormalized O-partial + per-row (m, l). Merge happens in pga_outproj.
// ---------------------------------------------------------------------------
#define KT_STRIDE 72
#define VN_STRIDE 76
#define PL_STRIDE 136

__global__ __launch_bounds__(256) void pga_attn(
    const float* __restrict__ Q, const float* __restrict__ K,
    const float* __restrict__ V, const float* __restrict__ biasg,
    const int* __restrict__ adj,
    float* __restrict__ op0, float* __restrict__ op1,
    float* __restrict__ op2, float* __restrict__ op3,
    float* __restrict__ mlbuf)
{
    __shared__ short Kt[128 * KT_STRIDE];
    __shared__ short Vn[128 * VN_STRIDE];
    __shared__ short Pl[4][16 * PL_STRIDE];

    const int blk = blockIdx.x;
    const int js = blk & 3;
    const int qt = (blk >> 2) & 7;
    const int h  = (blk >> 5) & 3;
    const int b  = blk >> 7;
    const int t = threadIdx.x;
    const int w = t >> 6;
    const int lane = t & 63;
    const int ln15 = lane & 15;
    const int quad = lane >> 4;

    float* Opart = (js == 0) ? op0 : (js == 1) ? op1 : (js == 2) ? op2 : op3;
    const int j0 = js * 128;
    const int i0w = qt * 64 + w * 16;

    // ---- Q A-fragments (scale folded into bf16 conversion) ----
    bf16x8 aq0, aq1;
    {
        const float* qrow = Q + ((size_t)(b * NTOK) + i0w + ln15) * HID + h * HD;
        const int k0 = quad * 8;
        #pragma unroll
        for (int jj = 0; jj < 8; ++jj) {
            aq0[jj] = f2bf(qrow[k0 + jj] * 0.125f);
            aq1[jj] = f2bf(qrow[32 + k0 + jj] * 0.125f);
        }
    }

    // ---- stage K,V tile ----
    for (int k = 0; k < 8; ++k) {
        const int flat4 = k * 256 + t;
        const int jl = flat4 >> 4, dq = flat4 & 15;
        const float4 kv = ((const float4*)(K + ((size_t)(b * NTOK) + j0 + jl) * HID + h * HD))[dq];
        const float4 vv = ((const float4*)(V + ((size_t)(b * NTOK) + j0 + jl) * HID + h * HD))[dq];
        bf16x4 ks, vs;
        ks[0] = f2bf(kv.x); ks[1] = f2bf(kv.y); ks[2] = f2bf(kv.z); ks[3] = f2bf(kv.w);
        vs[0] = f2bf(vv.x); vs[1] = f2bf(vv.y); vs[2] = f2bf(vv.z); vs[3] = f2bf(vv.w);
        *(bf16x4*)&Kt[jl * KT_STRIDE + dq * 4] = ks;
        *(bf16x4*)&Vn[jl * VN_STRIDE + dq * 4] = vs;
    }
    __syncthreads();

    // ---- S = Q K^T ----
    f32x4 s[8];
    #pragma unroll
    for (int nt = 0; nt < 8; ++nt) {
        const int krow = nt * 16 + ln15;
        const bf16x8 bk0 = *(const bf16x8*)&Kt[krow * KT_STRIDE + quad * 8];
        const bf16x8 bk1 = *(const bf16x8*)&Kt[krow * KT_STRIDE + 32 + quad * 8];
        f32x4 acc = (f32x4){0.f, 0.f, 0.f, 0.f};
        acc = __builtin_amdgcn_mfma_f32_16x16x32_bf16(aq0, bk0, acc, 0, 0, 0);
        acc = __builtin_amdgcn_mfma_f32_16x16x32_bf16(aq1, bk1, acc, 0, 0, 0);
        s[nt] = acc;
    }

    // ---- add masked bias ----
    const float* bgb = biasg + ((size_t)(b * HEADS + h)) * NTOK * NTOK;
    #pragma unroll
    for (int nt = 0; nt < 8; ++nt) {
        const int j = j0 + nt * 16 + ln15;
        #pragma unroll
        for (int r = 0; r < 4; ++r) {
            const int i = i0w + quad * 4 + r;
            const float bvv = bgb[(size_t)i * NTOK + j];
            const int mv = adj[i * NTOK + j];
            s[nt][r] += (mv > 0) ? bvv : NEG_INF;
        }
    }

    // ---- single-tile softmax stats ----
    float p[8][4], m_r[4], l_r[4];
    #pragma unroll
    for (int r = 0; r < 4; ++r) {
        float mx = s[0][r];
        #pragma unroll
        for (int nt = 1; nt < 8; ++nt) mx = fmaxf(mx, s[nt][r]);
        #pragma unroll
        for (int off = 1; off < 16; off <<= 1) mx = fmaxf(mx, __shfl_xor(mx, off, 64));
        float rs = 0.f;
        #pragma unroll
        for (int nt = 0; nt < 8; ++nt) { p[nt][r] = __expf(s[nt][r] - mx); rs += p[nt][r]; }
        #pragma unroll
        for (int off = 1; off < 16; off <<= 1) rs += __shfl_xor(rs, off, 64);
        m_r[r] = mx; l_r[r] = rs;
    }

    // ---- P -> per-wave LDS (C-layout scatter), read back as A-frags ----
    #pragma unroll
    for (int nt = 0; nt < 8; ++nt)
        #pragma unroll
        for (int r = 0; r < 4; ++r)
            Pl[w][(quad * 4 + r) * PL_STRIDE + nt * 16 + ln15] = f2bf(p[nt][r]);

    bf16x8 ap[4];
    #pragma unroll
    for (int kt = 0; kt < 4; ++kt)
        ap[kt] = *(const bf16x8*)&Pl[w][ln15 * PL_STRIDE + kt * 32 + quad * 8];

    // ---- O_partial = P V (unnormalized) ----
    f32x4 o_acc[4];
    #pragma unroll
    for (int dt = 0; dt < 4; ++dt) o_acc[dt] = (f32x4){0.f, 0.f, 0.f, 0.f};
    #pragma unroll
    for (int dt = 0; dt < 4; ++dt) {
        #pragma unroll
        for (int kt = 0; kt < 4; ++kt) {
            bf16x8 bv;
            #pragma unroll
            for (int jj = 0; jj < 8; ++jj)
                bv[jj] = Vn[(kt * 32 + quad * 8 + jj) * VN_STRIDE + dt * 16 + ln15];
            o_acc[dt] = __builtin_amdgcn_mfma_f32_16x16x32_bf16(ap[kt], bv, o_acc[dt], 0, 0, 0);
        }
    }

    // ---- write partials ----
    #pragma unroll
    for (int dt = 0; dt < 4; ++dt)
        #pragma unroll
        for (int r = 0; r < 4; ++r) {
            const int i = i0w + quad * 4 + r;
            Opart[((size_t)(b * NTOK) + i) * HID + h * HD + dt * 16 + ln15] = o_acc[dt][r];
        }
    if (ln15 == 0) {
        #pragma unroll
        for (int r = 0; r < 4; ++r) {
            const int i = i0w + quad * 4 + r;
            float* mlp = mlbuf + (((size_t)(js * BATCH + b) * NTOK + i) * HEADS + h) * 2;
            mlp[0] = m_r[r]; mlp[1] = l_r[r];
        }
    }
}

// ---------------------------------------------------------------------------
// Stage D: merge attention partials + out = O@Wo + bo.
//   256 blocks x 4 rows (1 block/CU): latency hidden by device-wide TLP.
// ---------------------------------------------------------------------------
__global__ __launch_bounds__(256) void pga_outproj(
    const float* __restrict__ op0, const float* __restrict__ op1,
    const float* __restrict__ op2, const float* __restrict__ op3,
    const float* __restrict__ mlbuf,
    const float* __restrict__ Wo, const float* __restrict__ bo,
    float* __restrict__ out)
{
    __shared__ float xs[4][HID];
    const int m0 = blockIdx.x * 4;
    const int t = threadIdx.x;
    const int c = t;                  // col for merge phase
    const int h = c >> 6;

    const float* ops[4] = {op0, op1, op2, op3};

    #pragma unroll
    for (int r = 0; r < 4; ++r) {
        const int ig = m0 + r;
        const int b = ig >> 9, i = ig & 511;
        float po[4], ms[4], ls[4];
        #pragma unroll
        for (int s = 0; s < 4; ++s) {
            po[s] = ops[s][(size_t)ig * HID + c];
            const float* mlp = mlbuf + (((size_t)(s * BATCH + b) * NTOK + i) * HEADS + h) * 2;
            ms[s] = mlp[0]; ls[s] = mlp[1];
        }
        const float mmax = fmaxf(fmaxf(ms[0], ms[1]), fmaxf(ms[2], ms[3]));
        float L = 0.f, val = 0.f;
        #pragma unroll
        for (int s = 0; s < 4; ++s) {
            const float e = __expf(ms[s] - mmax);
            L += ls[s] * e;
            val = fmaf(po[s], e, val);
        }
        xs[r][c] = val / L;
    }
    __syncthreads();

    const int cg = t & 63;
    const int rg = t >> 6;            // each thread: 1 row x 4 cols
    float4 acc = ((const float4*)bo)[cg];

    const float4* W4 = (const float4*)Wo;
    const float4* xrow = (const float4*)xs[rg];
    #pragma unroll 2
    for (int kq = 0; kq < 64; ++kq) {
        const float4 w0 = W4[(4 * kq + 0) * 64 + cg];
        const float4 w1 = W4[(4 * kq + 1) * 64 + cg];
        const float4 w2 = W4[(4 * kq + 2) * 64 + cg];
        const float4 w3 = W4[(4 * kq + 3) * 64 + cg];
        const float4 xv = xrow[kq];
        acc.x = fmaf(xv.x, w0.x, fmaf(xv.y, w1.x, fmaf(xv.z, w2.x, fmaf(xv.w, w3.x, acc.x))));
        acc.y = fmaf(xv.x, w0.y, fmaf(xv.y, w1.y, fmaf(xv.z, w2.y, fmaf(xv.w, w3.y, acc.y))));
        acc.z = fmaf(xv.x, w0.z, fmaf(xv.y, w1.z, fmaf(xv.z, w2.z, fmaf(xv.w, w3.z, acc.z))));
        acc.w = fmaf(xv.x, w0.w, fmaf(xv.y, w1.w, fmaf(xv.z, w2.w, fmaf(xv.w, w3.w, acc.w))));
    }
    ((float4*)(out + (m0 + rg) * HID))[cg] = acc;
}

extern "C" void kernel_launch(void* const* d_in, const int* in_sizes, int n_in,
                              void* d_out, int out_size, void* d_ws, size_t ws_size,
                              hipStream_t stream) {
    const float* x   = (const float*)d_in[0];
    const int*   adj = (const int*)d_in[1];
    const float* Wq  = (const float*)d_in[2];
    const float* bq  = (const float*)d_in[3];
    const float* Wk  = (const float*)d_in[4];
    const float* bk  = (const float*)d_in[5];
    const float* Wv  = (const float*)d_in[6];
    const float* bv  = (const float*)d_in[7];
    const float* Wo  = (const float*)d_in[8];
    const float* bo  = (const float*)d_in[9];
    const float* Wp1 = (const float*)d_in[10];
    const float* bp1 = (const float*)d_in[11];
    const float* Wp2 = (const float*)d_in[12];
    const float* bp2 = (const float*)d_in[13];
    float* out = (float*)d_out;

    // ws layout (floats), ~15.9 MB total. A/BbT die after pga_bias and are
    // reused as Opart[0]/Opart[1] by pga_attn (same-stream ordering).
    float* ws   = (float*)d_ws;
    float* Q    = ws;
    float* K    = ws + 262144;
    float* V    = ws + 2 * 262144;
    float* A    = ws + 3 * 262144;     // -> Opart[0]
    float* BbT  = ws + 4 * 262144;     // -> Opart[1]
    float* bias = ws + 5 * 262144;     // 2097152 floats
    float* Op2  = ws + 5 * 262144 + 2097152;
    float* Op3  = Op2 + 262144;
    float* mlb  = Op3 + 262144;        // 32768 floats

    pga_proj5<<<dim3(64, 5), 256, 0, stream>>>(x, Wq, bq, Wk, bk, Wv, bv,
                                               Wp1, bp1, Q, K, V, A, BbT);
    pga_bias<<<1024, 320, 0, stream>>>(A, BbT, Wp2, bp2, adj, bias);
    pga_attn<<<256, 256, 0, stream>>>(Q, K, V, bias, adj, A, BbT, Op2, Op3, mlb);
    pga_outproj<<<256, 256, 0, stream>>>(A, BbT, Op2, Op3, mlb, Wo, bo, out);
}